// Round 14
// baseline (87.024 us; speedup 1.0000x reference)
//
#include <hip/hip_runtime.h>
#include <hip/hip_bf16.h>
#include <math.h>
#include <stdint.h>

#define BV 4
#define NV 1024
#define IND 128
#define OUTD 128
#define NH 8
#define DD 16
#define LOG2E 1.4426950408889634f
#define REPA 6
#define REPB 3

typedef __attribute__((ext_vector_type(8))) short bf16x8;
typedef __attribute__((ext_vector_type(4))) float f32x4;

__device__ __forceinline__ ushort bf16rne(float f) {
    uint32_t u = __float_as_uint(f);
    u += 0x7fff + ((u >> 16) & 1);
    return (ushort)(u >> 16);
}

__device__ __forceinline__ uint32_t cvtpk_bf16(float lo, float hi) {
    uint32_t r;
    asm("v_cvt_pk_bf16_f32 %0, %1, %2" : "=v"(r) : "v"(lo), "v"(hi));
    return r;
}

__device__ __forceinline__ float vexp2(float x) {
    float r;
    asm("v_exp_f32 %0, %1" : "=v"(r) : "v"(x));
    return r;
}

// ---- kernel A: MEASUREMENT build — body repeated REPA times ----------------
__global__ __launch_bounds__(256) void kA(
    const float* __restrict__ x, const float* __restrict__ adj,
    const float* __restrict__ W, const float* __restrict__ a,
    uint32_t* __restrict__ bits, ushort* __restrict__ xhi,
    float* __restrict__ src, float* __restrict__ dst_t)
{
    const int pid = blockIdx.x;
    const int tid = threadIdx.x;

    __shared__ float xs[64][132];
    __shared__ float ws[128][16];
    __shared__ ushort thi[16][80];

    #pragma unroll 1
    for (int rep = 0; rep < REPA; ++rep) {
        asm volatile("" ::: "memory");
        if (pid >= 512) {
            const int row = pid - 512;
            const int i = row & (NV - 1);
            const int wave = tid >> 6, lane = tid & 63;
            const float* arow = adj + (size_t)row * NV;
            #pragma unroll
            for (int r = 0; r < 4; ++r) {
                const int j = (r * 4 + wave) * 64 + lane;
                const bool m = (arow[j] > 0.f) || (j == i);
                const unsigned long long bal = __ballot(m);
                if (lane == 0) {
                    bits[(size_t)row * 32 + (r * 4 + wave) * 2]     = (uint32_t)bal;
                    bits[(size_t)row * 32 + (r * 4 + wave) * 2 + 1] = (uint32_t)(bal >> 32);
                }
            }
            continue;
        }

        const int jt = pid & 15, bh = pid >> 4;
        const int b = bh >> 3, h = bh & 7;
        const int j0 = jt * 64;
        const int jl = tid >> 2, dq = tid & 3;

        {
            const float* xbase = x + ((size_t)(b * NV + j0)) * IND;
            #pragma unroll
            for (int t = 0; t < 8; ++t) {
                const int idx = tid + t * 256;
                const int row = idx >> 5, c4 = idx & 31;
                *(float4*)&xs[row][c4 * 4] = *(const float4*)&xbase[(size_t)row * IND + c4 * 4];
            }
            #pragma unroll
            for (int t = 0; t < 2; ++t) {
                const int idx = tid + t * 256;
                const int k = idx >> 2, dq4 = idx & 3;
                *(float4*)&ws[k][dq4 * 4] = *(const float4*)&W[(size_t)k * OUTD + h * DD + dq4 * 4];
            }
        }
        __syncthreads();

        float acc[4] = {0.f, 0.f, 0.f, 0.f};
        #pragma unroll 8
        for (int k = 0; k < IND; ++k) {
            const float xv = xs[jl][k];
            const float4 wv = *(const float4*)&ws[k][dq * 4];
            acc[0] = fmaf(xv, wv.x, acc[0]);
            acc[1] = fmaf(xv, wv.y, acc[1]);
            acc[2] = fmaf(xv, wv.z, acc[2]);
            acc[3] = fmaf(xv, wv.w, acc[3]);
        }

        const int gj = b * NV + j0 + jl;
        {
            const int d0 = dq * 4;
            float s = acc[0] * a[d0] + acc[1] * a[d0 + 1] + acc[2] * a[d0 + 2] + acc[3] * a[d0 + 3];
            float t = acc[0] * a[DD + d0] + acc[1] * a[DD + d0 + 1] + acc[2] * a[DD + d0 + 2] + acc[3] * a[DD + d0 + 3];
            s += __shfl_xor(s, 1); s += __shfl_xor(s, 2);
            t += __shfl_xor(t, 1); t += __shfl_xor(t, 2);
            if (dq == 0) {
                src[(size_t)gj * NH + h] = s * LOG2E;
                dst_t[(size_t)bh * NV + j0 + jl] = t * LOG2E;
            }
        }

        #pragma unroll
        for (int i2 = 0; i2 < 4; ++i2)
            thi[dq * 4 + i2][jl] = bf16rne(acc[i2]);
        __syncthreads();
        if (tid < 128) {
            const int d = tid >> 3, jo = tid & 7;
            const uint4 vh = *(const uint4*)&thi[d][jo * 8];
            const size_t base = ((size_t)(bh * 16 + d)) * NV + j0 + jo * 8;
            *(uint4*)&xhi[base] = vh;
        }
        __syncthreads();
    }
}

// --- kernel B: MEASUREMENT build — body repeated REPB times -----------------
__global__ __launch_bounds__(256, 6) void kB(
    const uint32_t* __restrict__ bits, const ushort* __restrict__ xhi,
    const float* __restrict__ dst_t, const float* __restrict__ src,
    float* __restrict__ out)
{
    const int bid = blockIdx.x;
    const int xcd = bid & 7, t2 = (bid >> 3) & 3, it = bid >> 5;
    const int bh = xcd * 4 + t2;
    const int b = bh >> 3, h = bh & 7;
    const int i0 = it * 16;

    const int tid = threadIdx.x;
    const int jq = tid >> 6, lane = tid & 63;
    const int g = lane >> 4, r16 = lane & 15;

    __shared__ float dstl[NV];
    __shared__ float mxr[4][16];
    __shared__ float red_acc[3][64][4];
    __shared__ float red_den[3][64];

    #pragma unroll 1
    for (int rep = 0; rep < REPB; ++rep) {
        asm volatile("" ::: "memory");
        {
            const float4* gd = (const float4*)(dst_t + (size_t)bh * NV);
            *(float4*)&dstl[tid * 4] = gd[tid];
        }
        const int grow = b * NV + i0 + r16;
        const float srcv = src[(size_t)grow * NH + h];
        uint32_t blw[8];
        #pragma unroll
        for (int s = 0; s < 8; ++s)
            blw[s] = bits[(size_t)grow * 32 + jq * 8 + s];
        __syncthreads();

        float dmax = -INFINITY;
        #pragma unroll
        for (int s = 0; s < 8; ++s) {
            const int base = jq * 256 + s * 32 + g * 8;
            const uint32_t bb = (blw[s] >> (g * 8)) & 0xffu;
            const float4 v0 = *(const float4*)&dstl[base];
            const float4 v1 = *(const float4*)&dstl[base + 4];
            const float dv[8] = {v0.x, v0.y, v0.z, v0.w, v1.x, v1.y, v1.z, v1.w};
            #pragma unroll
            for (int t = 0; t < 8; t += 2) {
                const float s0 = (bb & (1u << t)) ? dv[t] : -INFINITY;
                const float s1 = (bb & (1u << (t + 1))) ? dv[t + 1] : -INFINITY;
                dmax = fmaxf(dmax, fmaxf(s0, s1));
            }
        }
        dmax = fmaxf(dmax, __shfl_xor(dmax, 16));
        dmax = fmaxf(dmax, __shfl_xor(dmax, 32));
        if (g == 0) mxr[jq][r16] = dmax;
        __syncthreads();
        dmax = fmaxf(fmaxf(mxr[0][r16], mxr[1][r16]), fmaxf(mxr[2][r16], mxr[3][r16]));
        const float S = srcv + dmax;
        const float mxv = fmaxf(S, 0.2f * S);

        const float Ac = srcv - mxv;
        const float Bc = fmaf(0.2f, srcv, -mxv);
        f32x4 acc = {0.f, 0.f, 0.f, 0.f};
        float den0 = 0.f, den1 = 0.f;
        const ushort* xrow = xhi + ((size_t)(bh * 16 + r16)) * NV;
        #pragma unroll
        for (int s = 0; s < 8; ++s) {
            const int base = jq * 256 + s * 32 + g * 8;
            const uint32_t bb = (blw[s] >> (g * 8)) & 0xffu;
            const float4 v0 = *(const float4*)&dstl[base];
            const float4 v1 = *(const float4*)&dstl[base + 4];
            const float dv[8] = {v0.x, v0.y, v0.z, v0.w, v1.x, v1.y, v1.z, v1.w};
            float w[8];
            #pragma unroll
            for (int t = 0; t < 8; ++t) {
                const float arg = fmaxf(dv[t] + Ac, fmaf(0.2f, dv[t], Bc));
                const float argsel = (bb & (1u << t)) ? arg : 0.0f;
                w[t] = vexp2(argsel);
            }
            den0 += (w[0] + w[2]) + (w[4] + w[6]);
            den1 += (w[1] + w[3]) + (w[5] + w[7]);
            union { uint32_t u[4]; bf16x8 v; } af;
            af.u[0] = cvtpk_bf16(w[0], w[1]);
            af.u[1] = cvtpk_bf16(w[2], w[3]);
            af.u[2] = cvtpk_bf16(w[4], w[5]);
            af.u[3] = cvtpk_bf16(w[6], w[7]);
            const bf16x8 vh = *(const bf16x8*)&xrow[base];
            acc = __builtin_amdgcn_mfma_f32_16x16x32_bf16(af.v, vh, acc, 0, 0, 0);
        }
        float den = den0 + den1;

        if (jq > 0) {
            *(float4*)&red_acc[jq - 1][lane][0] = *(float4*)&acc;
            red_den[jq - 1][lane] = den;
        }
        __syncthreads();
        if (jq == 0) {
            #pragma unroll
            for (int qq = 0; qq < 3; ++qq) {
                const float4 oa = *(const float4*)&red_acc[qq][lane][0];
                acc[0] += oa.x; acc[1] += oa.y; acc[2] += oa.z; acc[3] += oa.w;
                den += red_den[qq][lane];
            }
            den += __shfl_xor(den, 16);
            den += __shfl_xor(den, 32);
            #pragma unroll
            for (int q = 0; q < 4; ++q) {
                const int orow = g * 4 + q;
                const float dq = __shfl(den, orow);
                float rv = acc[q] / dq;
                rv = fmaxf(rv, 0.f);
                out[((size_t)(b * NV) + i0 + orow) * OUTD + h * 16 + r16] = rv;
            }
        }
        __syncthreads();
    }
}

extern "C" void kernel_launch(void* const* d_in, const int* in_sizes, int n_in,
                              void* d_out, int out_size, void* d_ws, size_t ws_size,
                              hipStream_t stream)
{
    const float* x   = (const float*)d_in[0];
    const float* adj = (const float*)d_in[1];
    const float* W   = (const float*)d_in[2];
    const float* a   = (const float*)d_in[3];
    float* out = (float*)d_out;

    char* ws = (char*)d_ws;
    ushort* xhi    = (ushort*)ws;                                  // 1 MB
    float* dst_t   = (float*)(ws + 1024 * 1024);                   // 128 KB
    float* src     = (float*)(ws + 1024 * 1024 + 128 * 1024);      // 128 KB
    uint32_t* bits = (uint32_t*)(ws + 1024 * 1024 + 256 * 1024);   // 512 KB

    kA<<<512 + BV * NV, 256, 0, stream>>>(x, adj, W, a, bits, xhi, src, dst_t);
    kB<<<2048, 256, 0, stream>>>(bits, xhi, dst_t, src, out);
}

// Round 15
// 28.660 us; speedup vs baseline: 3.0364x; 3.0364x over previous
//
#include <hip/hip_runtime.h>
#include <hip/hip_bf16.h>
#include <math.h>
#include <stdint.h>

#define BV 4
#define NV 1024
#define IND 128
#define OUTD 128
#define NH 8
#define DD 16
#define LOG2E 1.4426950408889634f

typedef __attribute__((ext_vector_type(8))) short bf16x8;
typedef __attribute__((ext_vector_type(4))) float f32x4;

__device__ __forceinline__ ushort bf16rne(float f) {
    uint32_t u = __float_as_uint(f);
    u += 0x7fff + ((u >> 16) & 1);
    return (ushort)(u >> 16);
}

// pack two f32 -> two bf16 in one VALU inst (T12 recipe; no builtin on gfx950)
__device__ __forceinline__ uint32_t cvtpk_bf16(float lo, float hi) {
    uint32_t r;
    asm("v_cvt_pk_bf16_f32 %0, %1, %2" : "=v"(r) : "v"(lo), "v"(hi));
    return r;
}

// 2^x in one native TRANS instruction
__device__ __forceinline__ float vexp2(float x) {
    float r;
    asm("v_exp_f32 %0, %1" : "=v"(r) : "v"(x));
    return r;
}

// ---- kernel bits: mask bitwords, zero LDS, full occupancy ------------------
__global__ __launch_bounds__(256, 8) void kbits(
    const float* __restrict__ adj, uint32_t* __restrict__ bits)
{
    const int row = blockIdx.x;              // b*NV + i
    const int i = row & (NV - 1);
    const int wave = threadIdx.x >> 6, lane = threadIdx.x & 63;
    const float* arow = adj + (size_t)row * NV;
    #pragma unroll
    for (int r = 0; r < 4; ++r) {
        const int j = (r * 4 + wave) * 64 + lane;
        const bool m = (arow[j] > 0.f) || (j == i);
        const unsigned long long bal = __ballot(m);
        if (lane == 0) {
            bits[(size_t)row * 32 + (r * 4 + wave) * 2]     = (uint32_t)bal;
            bits[(size_t)row * 32 + (r * 4 + wave) * 2 + 1] = (uint32_t)(bal >> 32);
        }
    }
}

// ---- kernel proj: LDS-tiled projection + transpose + dots ------------------
__global__ __launch_bounds__(256) void kproj(
    const float* __restrict__ x, const float* __restrict__ W,
    const float* __restrict__ a, ushort* __restrict__ xhi,
    float* __restrict__ src, float* __restrict__ dst_t)
{
    const int pid = blockIdx.x;              // 512 blocks
    const int tid = threadIdx.x;
    const int jt = pid & 15, bh = pid >> 4;  // bh = b*8+h
    const int b = bh >> 3, h = bh & 7;
    const int j0 = jt * 64;
    const int jl = tid >> 2, dq = tid & 3;   // 4 threads per row, 4 d each

    __shared__ float xs[64][132];            // 33 KB, pad 132 -> 2-way max
    __shared__ float ws[128][16];            // 8 KB
    __shared__ ushort thi[16][80];           // 2.5 KB

    {   // stage x-tile: 2048 float4, coalesced
        const float* xbase = x + ((size_t)(b * NV + j0)) * IND;
        #pragma unroll
        for (int t = 0; t < 8; ++t) {
            const int idx = tid + t * 256;
            const int row = idx >> 5, c4 = idx & 31;
            *(float4*)&xs[row][c4 * 4] = *(const float4*)&xbase[(size_t)row * IND + c4 * 4];
        }
        // stage W-tile: 512 float4 (16 d's of head h across all 128 k)
        #pragma unroll
        for (int t = 0; t < 2; ++t) {
            const int idx = tid + t * 256;
            const int k = idx >> 2, dq4 = idx & 3;
            *(float4*)&ws[k][dq4 * 4] = *(const float4*)&W[(size_t)k * OUTD + h * DD + dq4 * 4];
        }
    }
    __syncthreads();

    float acc[4] = {0.f, 0.f, 0.f, 0.f};
    #pragma unroll 8
    for (int k = 0; k < IND; ++k) {
        const float xv = xs[jl][k];                      // broadcast + 2-way
        const float4 wv = *(const float4*)&ws[k][dq * 4];
        acc[0] = fmaf(xv, wv.x, acc[0]);
        acc[1] = fmaf(xv, wv.y, acc[1]);
        acc[2] = fmaf(xv, wv.z, acc[2]);
        acc[3] = fmaf(xv, wv.w, acc[3]);
    }

    // src/dst per-head dots (4-lane partial -> combine), pre-scaled by log2e
    const int gj = b * NV + j0 + jl;
    {
        const int d0 = dq * 4;
        float s = acc[0] * a[d0] + acc[1] * a[d0 + 1] + acc[2] * a[d0 + 2] + acc[3] * a[d0 + 3];
        float t = acc[0] * a[DD + d0] + acc[1] * a[DD + d0 + 1] + acc[2] * a[DD + d0 + 2] + acc[3] * a[DD + d0 + 3];
        s += __shfl_xor(s, 1); s += __shfl_xor(s, 2);
        t += __shfl_xor(t, 1); t += __shfl_xor(t, 2);
        if (dq == 0) {
            src[(size_t)gj * NH + h] = s * LOG2E;
            dst_t[(size_t)bh * NV + j0 + jl] = t * LOG2E;
        }
    }

    // bf16 round, transpose to [d][j] via small LDS tile
    #pragma unroll
    for (int i2 = 0; i2 < 4; ++i2)
        thi[dq * 4 + i2][jl] = bf16rne(acc[i2]);
    __syncthreads();
    if (tid < 128) {
        const int d = tid >> 3, jo = tid & 7;
        const uint4 vh = *(const uint4*)&thi[d][jo * 8];
        const size_t base = ((size_t)(bh * 16 + d)) * NV + j0 + jo * 8;
        *(uint4*)&xhi[base] = vh;
    }
}

// --- kernel B: r13 body, VGPR capped to 64 for 8 waves/SIMD -----------------
__global__ __launch_bounds__(256, 8) void kB(
    const uint32_t* __restrict__ bits, const ushort* __restrict__ xhi,
    const float* __restrict__ dst_t, const float* __restrict__ src,
    float* __restrict__ out)
{
    // grid 2048; XCD-swizzle: blocks on one XCD share 4 bh slabs
    const int bid = blockIdx.x;
    const int xcd = bid & 7, t2 = (bid >> 3) & 3, it = bid >> 5;
    const int bh = xcd * 4 + t2;             // 0..31
    const int b = bh >> 3, h = bh & 7;
    const int i0 = it * 16;

    const int tid = threadIdx.x;
    const int jq = tid >> 6, lane = tid & 63;  // wave = j-quarter
    const int g = lane >> 4, r16 = lane & 15;

    __shared__ float dstl[NV];               // 4 KB
    __shared__ float mxr[4][16];
    __shared__ float red_acc[3][64][4];      // 3 KB
    __shared__ float red_den[3][64];

    // ---- stage dstl + per-lane globals ----
    {
        const float4* gd = (const float4*)(dst_t + (size_t)bh * NV);
        *(float4*)&dstl[tid * 4] = gd[tid];
    }
    const int grow = b * NV + i0 + r16;      // this lane's i-row
    const float srcv = src[(size_t)grow * NH + h];
    uint32_t blw[8];
    #pragma unroll
    for (int s = 0; s < 8; ++s)
        blw[s] = bits[(size_t)grow * 32 + jq * 8 + s];
    __syncthreads();

    // ---- prepass: masked max of dst over this wave's j-quarter ----
    float dmax = -INFINITY;
    #pragma unroll
    for (int s = 0; s < 8; ++s) {
        const int base = jq * 256 + s * 32 + g * 8;
        const uint32_t bb = (blw[s] >> (g * 8)) & 0xffu;
        const float4 v0 = *(const float4*)&dstl[base];
        const float4 v1 = *(const float4*)&dstl[base + 4];
        const float dv[8] = {v0.x, v0.y, v0.z, v0.w, v1.x, v1.y, v1.z, v1.w};
        #pragma unroll
        for (int t = 0; t < 8; t += 2) {
            const float s0 = (bb & (1u << t)) ? dv[t] : -INFINITY;
            const float s1 = (bb & (1u << (t + 1))) ? dv[t + 1] : -INFINITY;
            dmax = fmaxf(dmax, fmaxf(s0, s1));   // invite v_max3
        }
    }
    dmax = fmaxf(dmax, __shfl_xor(dmax, 16));
    dmax = fmaxf(dmax, __shfl_xor(dmax, 32));
    if (g == 0) mxr[jq][r16] = dmax;
    __syncthreads();
    dmax = fmaxf(fmaxf(mxr[0][r16], mxr[1][r16]), fmaxf(mxr[2][r16], mxr[3][r16]));
    const float S = srcv + dmax;
    const float mxv = fmaxf(S, 0.2f * S);    // same op chain as per-element

    // ---- main loop: 8 iters over this wave's j-quarter ----
    // arg = lrelu(srcv+dv) - mxv = max(dv + A, fma(0.2,dv,B))
    const float Ac = srcv - mxv;
    const float Bc = fmaf(0.2f, srcv, -mxv);
    f32x4 acc = {0.f, 0.f, 0.f, 0.f};
    float den0 = 0.f, den1 = 0.f;
    const ushort* xrow = xhi + ((size_t)(bh * 16 + r16)) * NV;
    #pragma unroll
    for (int s = 0; s < 8; ++s) {
        const int base = jq * 256 + s * 32 + g * 8;
        const uint32_t bb = (blw[s] >> (g * 8)) & 0xffu;
        const float4 v0 = *(const float4*)&dstl[base];
        const float4 v1 = *(const float4*)&dstl[base + 4];
        const float dv[8] = {v0.x, v0.y, v0.z, v0.w, v1.x, v1.y, v1.z, v1.w};
        float w[8];
        #pragma unroll
        for (int t = 0; t < 8; ++t) {
            const float arg = fmaxf(dv[t] + Ac, fmaf(0.2f, dv[t], Bc));
            const float argsel = (bb & (1u << t)) ? arg : 0.0f;
            w[t] = vexp2(argsel);            // exp2(0)=1 exactly for unmasked
        }
        den0 += (w[0] + w[2]) + (w[4] + w[6]);
        den1 += (w[1] + w[3]) + (w[5] + w[7]);
        union { uint32_t u[4]; bf16x8 v; } af;
        af.u[0] = cvtpk_bf16(w[0], w[1]);
        af.u[1] = cvtpk_bf16(w[2], w[3]);
        af.u[2] = cvtpk_bf16(w[4], w[5]);
        af.u[3] = cvtpk_bf16(w[6], w[7]);
        const bf16x8 vh = *(const bf16x8*)&xrow[base];   // B-frag from L1/L2
        acc = __builtin_amdgcn_mfma_f32_16x16x32_bf16(af.v, vh, acc, 0, 0, 0);
    }
    float den = den0 + den1;

    // ---- epilogue: cross-quarter reduce + normalize + relu + store ----
    if (jq > 0) {
        *(float4*)&red_acc[jq - 1][lane][0] = *(float4*)&acc;
        red_den[jq - 1][lane] = den;
    }
    __syncthreads();
    if (jq == 0) {
        #pragma unroll
        for (int qq = 0; qq < 3; ++qq) {
            const float4 oa = *(const float4*)&red_acc[qq][lane][0];
            acc[0] += oa.x; acc[1] += oa.y; acc[2] += oa.z; acc[3] += oa.w;
            den += red_den[qq][lane];
        }
        den += __shfl_xor(den, 16);
        den += __shfl_xor(den, 32);           // full-row den at matching r16
        #pragma unroll
        for (int q = 0; q < 4; ++q) {
            const int orow = g * 4 + q;       // C row for this lane
            const float dq = __shfl(den, orow);
            float rv = acc[q] / dq;
            rv = fmaxf(rv, 0.f);
            out[((size_t)(b * NV) + i0 + orow) * OUTD + h * 16 + r16] = rv;
        }
    }
}

extern "C" void kernel_launch(void* const* d_in, const int* in_sizes, int n_in,
                              void* d_out, int out_size, void* d_ws, size_t ws_size,
                              hipStream_t stream)
{
    const float* x   = (const float*)d_in[0];
    const float* adj = (const float*)d_in[1];
    const float* W   = (const float*)d_in[2];
    const float* a   = (const float*)d_in[3];
    float* out = (float*)d_out;

    char* ws = (char*)d_ws;
    ushort* xhi    = (ushort*)ws;                                  // 1 MB
    float* dst_t   = (float*)(ws + 1024 * 1024);                   // 128 KB
    float* src     = (float*)(ws + 1024 * 1024 + 128 * 1024);      // 128 KB
    uint32_t* bits = (uint32_t*)(ws + 1024 * 1024 + 256 * 1024);   // 512 KB

    kproj<<<512, 256, 0, stream>>>(x, W, a, xhi, src, dst_t);
    kbits<<<BV * NV, 256, 0, stream>>>(adj, bits);
    kB<<<2048, 256, 0, stream>>>(bits, xhi, dst_t, src, out);
}

// Round 16
// 26.135 us; speedup vs baseline: 3.3298x; 1.0966x over previous
//
#include <hip/hip_runtime.h>
#include <hip/hip_bf16.h>
#include <math.h>
#include <stdint.h>

#define BV 4
#define NV 1024
#define IND 128
#define OUTD 128
#define NH 8
#define DD 16
#define LOG2E 1.4426950408889634f

typedef __attribute__((ext_vector_type(8))) short bf16x8;
typedef __attribute__((ext_vector_type(4))) float f32x4;

__device__ __forceinline__ ushort bf16rne(float f) {
    uint32_t u = __float_as_uint(f);
    u += 0x7fff + ((u >> 16) & 1);
    return (ushort)(u >> 16);
}

// pack two f32 -> two bf16 in one VALU inst (T12 recipe; no builtin on gfx950)
__device__ __forceinline__ uint32_t cvtpk_bf16(float lo, float hi) {
    uint32_t r;
    asm("v_cvt_pk_bf16_f32 %0, %1, %2" : "=v"(r) : "v"(lo), "v"(hi));
    return r;
}

// 2^x in one native TRANS instruction
__device__ __forceinline__ float vexp2(float x) {
    float r;
    asm("v_exp_f32 %0, %1" : "=v"(r) : "v"(x));
    return r;
}

// ---- kernel A: fused {bits (pid<4096) | proj (pid>=4096)}, 10.5 KB LDS -----
__global__ __launch_bounds__(256) void kA(
    const float* __restrict__ x, const float* __restrict__ adj,
    const float* __restrict__ W, const float* __restrict__ a,
    uint32_t* __restrict__ bits, ushort* __restrict__ xhi,
    float* __restrict__ src, float* __restrict__ dst_t)
{
    const int pid = blockIdx.x;
    const int tid = threadIdx.x;

    __shared__ float ws[128][16];            // 8 KB (proj path only)
    __shared__ ushort thi[16][80];           // 2.5 KB

    if (pid < BV * NV) {
        // ---------------- mask bitwords (diagonal forced in) ----------------
        // dispatched first: HBM-bound adj stream starts immediately
        const int row = pid;                 // b*NV + i
        const int i = row & (NV - 1);
        const int wave = tid >> 6, lane = tid & 63;
        const float* arow = adj + (size_t)row * NV;
        #pragma unroll
        for (int r = 0; r < 4; ++r) {
            const int j = (r * 4 + wave) * 64 + lane;
            const bool m = (arow[j] > 0.f) || (j == i);
            const unsigned long long bal = __ballot(m);
            if (lane == 0) {
                bits[(size_t)row * 32 + (r * 4 + wave) * 2]     = (uint32_t)bal;
                bits[(size_t)row * 32 + (r * 4 + wave) * 2 + 1] = (uint32_t)(bal >> 32);
            }
        }
        return;
    }

    // ------------- projection: 64-row x 16-d tile, W in LDS -----------------
    const int p = pid - BV * NV;             // 0..511
    const int jt = p & 15, bh = p >> 4;      // bh = b*8+h
    const int b = bh >> 3, h = bh & 7;
    const int j0 = jt * 64;
    const int jl = tid >> 2, dq = tid & 3;   // 4 threads per row, 4 d each

    {   // stage W-tile: 512 float4 (16 d's of head h across all 128 k)
        #pragma unroll
        for (int t = 0; t < 2; ++t) {
            const int idx = tid + t * 256;
            const int k = idx >> 2, dq4 = idx & 3;
            *(float4*)&ws[k][dq4 * 4] = *(const float4*)&W[(size_t)k * OUTD + h * DD + dq4 * 4];
        }
    }
    __syncthreads();

    // per-thread x-row read (32-float register chunks), ws from LDS
    float acc[4] = {0.f, 0.f, 0.f, 0.f};
    const float* xrow = x + ((size_t)(b * NV + j0 + jl)) * IND;
    #pragma unroll
    for (int kc = 0; kc < IND; kc += 32) {
        float4 xr[8];
        #pragma unroll
        for (int u = 0; u < 8; ++u)
            xr[u] = *(const float4*)&xrow[kc + u * 4];
        #pragma unroll
        for (int u = 0; u < 8; ++u) {
            #pragma unroll
            for (int v = 0; v < 4; ++v) {
                const float xv = ((const float*)&xr[u])[v];
                const float4 wv = *(const float4*)&ws[kc + u * 4 + v][dq * 4];
                acc[0] = fmaf(xv, wv.x, acc[0]);
                acc[1] = fmaf(xv, wv.y, acc[1]);
                acc[2] = fmaf(xv, wv.z, acc[2]);
                acc[3] = fmaf(xv, wv.w, acc[3]);
            }
        }
    }

    // src/dst per-head dots (4-lane partial -> combine), pre-scaled by log2e
    const int gj = b * NV + j0 + jl;
    {
        const int d0 = dq * 4;
        float s = acc[0] * a[d0] + acc[1] * a[d0 + 1] + acc[2] * a[d0 + 2] + acc[3] * a[d0 + 3];
        float t = acc[0] * a[DD + d0] + acc[1] * a[DD + d0 + 1] + acc[2] * a[DD + d0 + 2] + acc[3] * a[DD + d0 + 3];
        s += __shfl_xor(s, 1); s += __shfl_xor(s, 2);
        t += __shfl_xor(t, 1); t += __shfl_xor(t, 2);
        if (dq == 0) {
            src[(size_t)gj * NH + h] = s * LOG2E;
            dst_t[(size_t)bh * NV + j0 + jl] = t * LOG2E;
        }
    }

    // bf16 round, transpose to [d][j] via small LDS tile
    #pragma unroll
    for (int i2 = 0; i2 < 4; ++i2)
        thi[dq * 4 + i2][jl] = bf16rne(acc[i2]);
    __syncthreads();
    if (tid < 128) {
        const int d = tid >> 3, jo = tid & 7;
        const uint4 vh = *(const uint4*)&thi[d][jo * 8];
        const size_t base = ((size_t)(bh * 16 + d)) * NV + j0 + jo * 8;
        *(uint4*)&xhi[base] = vh;
    }
}

// --- kernel B: r13 body exactly, (256,6) ------------------------------------
__global__ __launch_bounds__(256, 6) void kB(
    const uint32_t* __restrict__ bits, const ushort* __restrict__ xhi,
    const float* __restrict__ dst_t, const float* __restrict__ src,
    float* __restrict__ out)
{
    // grid 2048; XCD-swizzle: blocks on one XCD share 4 bh slabs
    const int bid = blockIdx.x;
    const int xcd = bid & 7, t2 = (bid >> 3) & 3, it = bid >> 5;
    const int bh = xcd * 4 + t2;             // 0..31
    const int b = bh >> 3, h = bh & 7;
    const int i0 = it * 16;

    const int tid = threadIdx.x;
    const int jq = tid >> 6, lane = tid & 63;  // wave = j-quarter
    const int g = lane >> 4, r16 = lane & 15;

    __shared__ float dstl[NV];               // 4 KB
    __shared__ float mxr[4][16];
    __shared__ float red_acc[3][64][4];      // 3 KB
    __shared__ float red_den[3][64];

    // ---- stage dstl + per-lane globals ----
    {
        const float4* gd = (const float4*)(dst_t + (size_t)bh * NV);
        *(float4*)&dstl[tid * 4] = gd[tid];
    }
    const int grow = b * NV + i0 + r16;      // this lane's i-row
    const float srcv = src[(size_t)grow * NH + h];
    uint32_t blw[8];
    #pragma unroll
    for (int s = 0; s < 8; ++s)
        blw[s] = bits[(size_t)grow * 32 + jq * 8 + s];
    __syncthreads();

    // ---- prepass: masked max of dst over this wave's j-quarter ----
    float dmax = -INFINITY;
    #pragma unroll
    for (int s = 0; s < 8; ++s) {
        const int base = jq * 256 + s * 32 + g * 8;
        const uint32_t bb = (blw[s] >> (g * 8)) & 0xffu;
        const float4 v0 = *(const float4*)&dstl[base];
        const float4 v1 = *(const float4*)&dstl[base + 4];
        const float dv[8] = {v0.x, v0.y, v0.z, v0.w, v1.x, v1.y, v1.z, v1.w};
        #pragma unroll
        for (int t = 0; t < 8; t += 2) {
            const float s0 = (bb & (1u << t)) ? dv[t] : -INFINITY;
            const float s1 = (bb & (1u << (t + 1))) ? dv[t + 1] : -INFINITY;
            dmax = fmaxf(dmax, fmaxf(s0, s1));   // invite v_max3
        }
    }
    dmax = fmaxf(dmax, __shfl_xor(dmax, 16));
    dmax = fmaxf(dmax, __shfl_xor(dmax, 32));
    if (g == 0) mxr[jq][r16] = dmax;
    __syncthreads();
    dmax = fmaxf(fmaxf(mxr[0][r16], mxr[1][r16]), fmaxf(mxr[2][r16], mxr[3][r16]));
    const float S = srcv + dmax;
    const float mxv = fmaxf(S, 0.2f * S);    // same op chain as per-element

    // ---- main loop: 8 iters over this wave's j-quarter ----
    // arg = lrelu(srcv+dv) - mxv = max(dv + A, fma(0.2,dv,B))
    const float Ac = srcv - mxv;
    const float Bc = fmaf(0.2f, srcv, -mxv);
    f32x4 acc = {0.f, 0.f, 0.f, 0.f};
    float den0 = 0.f, den1 = 0.f;
    const ushort* xrow = xhi + ((size_t)(bh * 16 + r16)) * NV;
    #pragma unroll
    for (int s = 0; s < 8; ++s) {
        const int base = jq * 256 + s * 32 + g * 8;
        const uint32_t bb = (blw[s] >> (g * 8)) & 0xffu;
        const float4 v0 = *(const float4*)&dstl[base];
        const float4 v1 = *(const float4*)&dstl[base + 4];
        const float dv[8] = {v0.x, v0.y, v0.z, v0.w, v1.x, v1.y, v1.z, v1.w};
        float w[8];
        #pragma unroll
        for (int t = 0; t < 8; ++t) {
            const float arg = fmaxf(dv[t] + Ac, fmaf(0.2f, dv[t], Bc));
            const float argsel = (bb & (1u << t)) ? arg : 0.0f;
            w[t] = vexp2(argsel);            // exp2(0)=1 exactly for unmasked
        }
        den0 += (w[0] + w[2]) + (w[4] + w[6]);
        den1 += (w[1] + w[3]) + (w[5] + w[7]);
        union { uint32_t u[4]; bf16x8 v; } af;
        af.u[0] = cvtpk_bf16(w[0], w[1]);
        af.u[1] = cvtpk_bf16(w[2], w[3]);
        af.u[2] = cvtpk_bf16(w[4], w[5]);
        af.u[3] = cvtpk_bf16(w[6], w[7]);
        const bf16x8 vh = *(const bf16x8*)&xrow[base];   // B-frag from L1/L2
        acc = __builtin_amdgcn_mfma_f32_16x16x32_bf16(af.v, vh, acc, 0, 0, 0);
    }
    float den = den0 + den1;

    // ---- epilogue: cross-quarter reduce + normalize + relu + store ----
    if (jq > 0) {
        *(float4*)&red_acc[jq - 1][lane][0] = *(float4*)&acc;
        red_den[jq - 1][lane] = den;
    }
    __syncthreads();
    if (jq == 0) {
        #pragma unroll
        for (int qq = 0; qq < 3; ++qq) {
            const float4 oa = *(const float4*)&red_acc[qq][lane][0];
            acc[0] += oa.x; acc[1] += oa.y; acc[2] += oa.z; acc[3] += oa.w;
            den += red_den[qq][lane];
        }
        den += __shfl_xor(den, 16);
        den += __shfl_xor(den, 32);           // full-row den at matching r16
        #pragma unroll
        for (int q = 0; q < 4; ++q) {
            const int orow = g * 4 + q;       // C row for this lane
            const float dq = __shfl(den, orow);
            float rv = acc[q] / dq;
            rv = fmaxf(rv, 0.f);
            out[((size_t)(b * NV) + i0 + orow) * OUTD + h * 16 + r16] = rv;
        }
    }
}

extern "C" void kernel_launch(void* const* d_in, const int* in_sizes, int n_in,
                              void* d_out, int out_size, void* d_ws, size_t ws_size,
                              hipStream_t stream)
{
    const float* x   = (const float*)d_in[0];
    const float* adj = (const float*)d_in[1];
    const float* W   = (const float*)d_in[2];
    const float* a   = (const float*)d_in[3];
    float* out = (float*)d_out;

    char* ws = (char*)d_ws;
    ushort* xhi    = (ushort*)ws;                                  // 1 MB
    float* dst_t   = (float*)(ws + 1024 * 1024);                   // 128 KB
    float* src     = (float*)(ws + 1024 * 1024 + 128 * 1024);      // 128 KB
    uint32_t* bits = (uint32_t*)(ws + 1024 * 1024 + 256 * 1024);   // 512 KB

    kA<<<BV * NV + 512, 256, 0, stream>>>(x, adj, W, a, bits, xhi, src, dst_t);
    kB<<<2048, 256, 0, stream>>>(bits, xhi, dst_t, src, out);
}